// Round 8
// baseline (280.245 us; speedup 1.0000x reference)
//
#include <hip/hip_runtime.h>
#include <cstdint>
#include <cstddef>

#define CD   512
#define BDIM 16
#define NQ   1024
#define NP   1024
#define NUP  2048

typedef unsigned short u16;
typedef short short8 __attribute__((ext_vector_type(8)));
typedef float f32x4  __attribute__((ext_vector_type(4)));
typedef uint32_t u32x4 __attribute__((ext_vector_type(4)));

#define GLOAD16(g, l) __builtin_amdgcn_global_load_lds( \
    (const __attribute__((address_space(1))) void*)(g), \
    (__attribute__((address_space(3))) void*)(l), 16, 0, 0)

__device__ __forceinline__ u16 rne_bf16(float x) {
  uint32_t u = __float_as_uint(x);
  return (u16)((u + 0x7fffu + ((u >> 16) & 1u)) >> 16);
}
__device__ __forceinline__ float bf2f(u16 v) {
  return __uint_as_float(((uint32_t)v) << 16);
}

// ---------------------------------------------------- prep: conversions + 3-NN
// bx < 8832: fp32->bf16 conversions (query, key, 5 weights).
// bx >= 8832: 512 knn blocks (compute-bound; overlaps the memory-bound convs).
__global__ __launch_bounds__(256) void prep_kernel(
    const float* __restrict__ query, u16* __restrict__ Qa,
    const float* __restrict__ key, u16* __restrict__ Ka,
    const float* __restrict__ Wq, const float* __restrict__ Wkv1,
    const float* __restrict__ projw, const float* __restrict__ fpw,
    const float* __restrict__ wkv2, u16* __restrict__ Wq2,
    u16* __restrict__ Wkv12, u16* __restrict__ proj2,
    u16* __restrict__ fpwb, u16* __restrict__ wkv2b,
    const float* __restrict__ key_pos, const float* __restrict__ xyz_up,
    int* __restrict__ idx_out, float* __restrict__ w_out)
{
  const int bx = blockIdx.x;
  const int tid = threadIdx.x;
  if (bx < 8832) {
    const float* in; u16* out; float scl = 1.0f; long u;
    if (bx < 8192) {
      in = (bx < 4096) ? query : key;
      out = (bx < 4096) ? Qa : Ka;
      u = (long)(bx & 4095) * 256 + tid;
    } else {
      const int job = (bx - 8192) >> 7;
      in  = (job == 0) ? Wq  : (job == 1) ? Wkv1  : (job == 2) ? projw : (job == 3) ? fpw  : wkv2;
      out = (job == 0) ? Wq2 : (job == 1) ? Wkv12 : (job == 2) ? proj2 : (job == 3) ? fpwb : wkv2b;
      if (job == 0) scl = 0.18033688011112042f;   // 0.125 * log2(e)
      u = (long)((bx - 8192) & 127) * 256 + tid;
    }
    const float* ip = in + u * 8;
    float v[8];
    *(float4*)&v[0] = *(const float4*)ip;
    *(float4*)&v[4] = *(const float4*)(ip + 4);
    short8 o;
#pragma unroll
    for (int i = 0; i < 8; ++i) o[i] = (short)rne_bf16(v[i] * scl);
    *(short8*)(out + u * 8) = o;
    return;
  }
  // ---- 3-NN path
  __shared__ float kp[NP * 3];
  __shared__ float dsh[64][4][3];
  __shared__ int   ish[64][4][3];
  const int bid = bx - 8832;
  const int kx = bid & 31, b = bid >> 5;
#pragma unroll
  for (int s = 0; s < (NP * 3) / 256; ++s)
    kp[s * 256 + tid] = key_pos[b * NP * 3 + s * 256 + tid];
  __syncthreads();
  const int pt = tid >> 2, sc = tid & 3;
  const int n = kx * 64 + pt;
  const float ux = xyz_up[(b * NUP + n) * 3 + 0];
  const float uy = xyz_up[(b * NUP + n) * 3 + 1];
  const float uz = xyz_up[(b * NUP + n) * 3 + 2];
  float d0 = 3.4e38f, d1 = 3.4e38f, d2b = 3.4e38f;
  int i0 = 0, i1 = 0, i2 = 0;
  for (int j = sc * 256; j < sc * 256 + 256; ++j) {
    const float dx = ux - kp[j * 3 + 0];
    const float dy = uy - kp[j * 3 + 1];
    const float dz = uz - kp[j * 3 + 2];
    const float dd = dx * dx + dy * dy + dz * dz;
    if (dd < d2b) {
      if (dd < d1) {
        d2b = d1; i2 = i1;
        if (dd < d0) { d1 = d0; i1 = i0; d0 = dd; i0 = j; }
        else         { d1 = dd; i1 = j; }
      } else { d2b = dd; i2 = j; }
    }
  }
  dsh[pt][sc][0] = d0;  dsh[pt][sc][1] = d1;  dsh[pt][sc][2] = d2b;
  ish[pt][sc][0] = i0;  ish[pt][sc][1] = i1;  ish[pt][sc][2] = i2;
  __syncthreads();
  if (sc == 0) {
    float e0 = 3.4e38f, e1 = 3.4e38f, e2 = 3.4e38f;
    int   j0 = 0, j1 = 0, j2 = 0;
#pragma unroll
    for (int s = 0; s < 4; ++s)
#pragma unroll
      for (int t = 0; t < 3; ++t) {
        const float dd = dsh[pt][s][t];
        const int   jj = ish[pt][s][t];
        if (dd < e2) {
          if (dd < e1) {
            e2 = e1; j2 = j1;
            if (dd < e0) { e1 = e0; j1 = j0; e0 = dd; j0 = jj; }
            else         { e1 = dd; j1 = jj; }
          } else { e2 = dd; j2 = jj; }
        }
      }
    const float w0 = 1.0f / (e0 + 1e-8f);
    const float w1 = 1.0f / (e1 + 1e-8f);
    const float w2 = 1.0f / (e2 + 1e-8f);
    const float inv = 1.0f / ((w0 + w1) + w2);
    const long r = (long)b * NUP + n;
    idx_out[r * 3 + 0] = j0; idx_out[r * 3 + 1] = j1; idx_out[r * 3 + 2] = j2;
    w_out[r * 3 + 0] = w0 * inv; w_out[r * 3 + 1] = w1 * inv; w_out[r * 3 + 2] = w2 * inv;
  }
}

// ------------------------------------------------- interp (bf16 in/out)
__global__ __launch_bounds__(256) void interp_bf16_kernel(
    const u16* __restrict__ Ka, const int* __restrict__ idx,
    const float* __restrict__ w, u16* __restrict__ out)
{
  const int t = threadIdx.x;
  const long r = (long)blockIdx.x * 4 + (t >> 6);
  const int j = t & 63;
  const int b = (int)(r >> 11);
  const int j0 = idx[r * 3 + 0], j1 = idx[r * 3 + 1], j2 = idx[r * 3 + 2];
  const float w0 = w[r * 3 + 0], w1 = w[r * 3 + 1], w2 = w[r * 3 + 2];
  const short8 a0 = *(const short8*)(Ka + ((long)j0 * BDIM + b) * CD + j * 8);
  const short8 a1 = *(const short8*)(Ka + ((long)j1 * BDIM + b) * CD + j * 8);
  const short8 a2 = *(const short8*)(Ka + ((long)j2 * BDIM + b) * CD + j * 8);
  short8 o;
#pragma unroll
  for (int i = 0; i < 8; ++i)
    o[i] = (short)rne_bf16(bf2f((u16)a0[i]) * w0 + bf2f((u16)a1[i]) * w1
                         + bf2f((u16)a2[i]) * w2);
  *(short8*)(out + r * CD + j * 8) = o;
}

// ---------------------------------------------------------------- GEMM BK=64
// 128x128 tile, BK=64, 4 waves: 2 barriers per 32 MFMA (was per 16).
// LDS rows 128B wide, sigma = row&7 XOR swizzle via pre-permuted global src.
template<int AMODE, int OMODE, int KE>
__device__ __forceinline__ void gemm_body64(
    u16* __restrict__ As, u16* __restrict__ Ws,
    const u16* __restrict__ A, const u16* __restrict__ W,
    const float* __restrict__ bias, void* __restrict__ outv,
    const int m0, const int n0)
{
  const int tid = threadIdx.x;
  const int lane = tid & 63, wv = tid >> 6;
  const int rch = tid & 7;

  f32x4 acc[4][4];
#pragma unroll
  for (int mi = 0; mi < 4; ++mi)
#pragma unroll
    for (int ni = 0; ni < 4; ++ni)
#pragma unroll
      for (int r = 0; r < 4; ++r) acc[mi][ni][r] = 0.0f;

  const long rowb = (long)KE * 2;
  const char* gA[4]; const char* gW[4];
#pragma unroll
  for (int s = 0; s < 4; ++s) {
    const int row = s * 32 + (tid >> 3);
    const int gm = m0 + row;
    const long arow = (AMODE == 0) ? (long)gm : (long)(gm & 15) * 2048 + (gm >> 4);
    const int kb0 = (rch ^ (row & 7)) << 4;
    gA[s] = (const char*)A + arow * rowb + kb0;
    gW[s] = (const char*)W + (long)(n0 + row) * rowb + kb0;
  }
  const int wr = (wv >> 1) * 64, wc = (wv & 1) * 64;
  const int g = lane >> 4, cl = lane & 15;

  for (int kt = 0; kt < KE / 64; ++kt) {
#pragma unroll
    for (int s = 0; s < 4; ++s) {
      GLOAD16(gA[s], (char*)As + (s * 256 + tid) * 16);
      GLOAD16(gW[s], (char*)Ws + (s * 256 + tid) * 16);
      gA[s] += 128; gW[s] += 128;
    }
    __syncthreads();
#pragma unroll
    for (int kb = 0; kb < 2; ++kb) {
      short8 af[4], bf[4];
#pragma unroll
      for (int i = 0; i < 4; ++i) {
        const int ra = wr + i * 16 + cl;
        af[i] = *(const short8*)((const char*)As + ra * 128
                 + ((kb * 64 + g * 16) ^ ((ra & 7) << 4)));
        const int rb = wc + i * 16 + cl;
        bf[i] = *(const short8*)((const char*)Ws + rb * 128
                 + ((kb * 64 + g * 16) ^ ((rb & 7) << 4)));
      }
#pragma unroll
      for (int mi = 0; mi < 4; ++mi)
#pragma unroll
        for (int ni = 0; ni < 4; ++ni)
          acc[mi][ni] = __builtin_amdgcn_mfma_f32_16x16x32_bf16(af[mi], bf[ni], acc[mi][ni], 0, 0, 0);
    }
    __syncthreads();
  }

#pragma unroll
  for (int mi = 0; mi < 4; ++mi)
#pragma unroll
    for (int ni = 0; ni < 4; ++ni)
#pragma unroll
      for (int r = 0; r < 4; ++r) {
        const int gm = m0 + wr + mi * 16 + g * 4 + r;
        const int gn = n0 + wc + ni * 16 + cl;
        float v = acc[mi][ni][r];
        if (OMODE == 0) {
          ((u16*)outv)[(long)gm * 512 + gn] = rne_bf16(v);
        } else if (OMODE == 1) {
          v = fmaxf(v + bias[gn], 0.0f);
          ((u16*)outv)[(long)gm * 512 + gn] = rne_bf16(v);
        } else {
          v += bias[gn];
          ((float*)outv)[((long)(gm & 1023) * BDIM + (gm >> 10)) * 512 + gn] = v;
        }
      }
}

// fp-GEMM (1024 blocks) + q-GEMM (512) + kv1-GEMM (512) in one launch
__global__ __launch_bounds__(256) void gemm_mega_kernel(
    const u16* __restrict__ IN2, const u16* __restrict__ fpwb,
    const float* __restrict__ fp_b, u16* __restrict__ KEY2,
    const u16* __restrict__ Qa, const u16* __restrict__ Wq2, u16* __restrict__ Qb,
    const u16* __restrict__ Ka, const u16* __restrict__ Wkv12, u16* __restrict__ KV1)
{
  __shared__ __align__(16) u16 As[128 * 64];
  __shared__ __align__(16) u16 Ws[128 * 64];
  const int bid = blockIdx.x;
  if (bid < 1024) {
    gemm_body64<0, 1, 512>(As, Ws, IN2, fpwb, fp_b, KEY2, (bid >> 2) * 128, (bid & 3) * 128);
  } else if (bid < 1536) {
    const int t = bid - 1024;
    gemm_body64<0, 0, 512>(As, Ws, Qa, Wq2, nullptr, Qb, (t >> 2) * 128, (t & 3) * 128);
  } else {
    const int t = bid - 1536;
    gemm_body64<0, 0, 512>(As, Ws, Ka, Wkv12, nullptr, KV1, (t >> 2) * 128, (t & 3) * 128);
  }
}

// ------------------------------------------------- V transpose body
__device__ __forceinline__ void transpose_body(
    u16* __restrict__ L, const u16* __restrict__ KV, u16* __restrict__ Vt,
    const int NK, const int kt, const int h, const int b)
{
  const int t = threadIdx.x;
  {
    const int n = t >> 2, d0 = (t & 3) * 16;
    const u16* src = KV + ((size_t)b * NK + kt * 64 + n) * 512 + 256 + h * 64 + d0;
    *(short8*)&L[n * 68 + d0] = *(const short8*)src;
    *(short8*)&L[n * 68 + d0 + 8] = *(const short8*)(src + 8);
  }
  __syncthreads();
  const int d = t >> 2, n0 = (t & 3) * 16;
  short8 o0, o1;
#pragma unroll
  for (int i = 0; i < 8; ++i) {
    o0[i] = (short)L[(n0 + i) * 68 + d];
    o1[i] = (short)L[(n0 + 8 + i) * 68 + d];
  }
  u16* dst = Vt + ((size_t)((b * 4 + h) * 64 + d)) * NK + kt * 64 + n0;
  *(short8*)dst = o0; *(short8*)(dst + 8) = o1;
}

// kv2-GEMM (1024 blocks) + Vt1 transpose (1024 blocks): independent jobs
__global__ __launch_bounds__(256) void gemm_kv2_vt1_kernel(
    const u16* __restrict__ KEY2, const u16* __restrict__ wkv2b,
    u16* __restrict__ KV2,
    const u16* __restrict__ KV1, u16* __restrict__ Vt1)
{
  __shared__ __align__(16) u16 As[128 * 64];
  __shared__ __align__(16) u16 Ws[128 * 64];
  const int bid = blockIdx.x;
  if (bid < 1024) {
    gemm_body64<1, 0, 512>(As, Ws, KEY2, wkv2b, nullptr, KV2,
                           (bid >> 2) * 128, (bid & 3) * 128);
  } else {
    const int tb = bid - 1024;
    transpose_body(As, KV1, Vt1, 1024, tb & 15, (tb >> 4) & 3, tb >> 6);
  }
}

__global__ __launch_bounds__(256) void vt2_kernel(
    const u16* __restrict__ KV2, u16* __restrict__ Vt2)
{
  __shared__ u16 L[64 * 68];
  transpose_body(L, KV2, Vt2, 2048, blockIdx.x, blockIdx.y, blockIdx.z);
}

// ------------------------------------------------- proj GEMM, 64x128 tiles
__global__ __launch_bounds__(256) void gemm_proj64_kernel(
    const u16* __restrict__ A, const u16* __restrict__ W,
    const float* __restrict__ bias, float* __restrict__ out)
{
  __shared__ __align__(16) u16 As[64 * 32];
  __shared__ __align__(16) u16 Ws[128 * 32];
  const int tid = threadIdx.x;
  const int lane = tid & 63, wv = tid >> 6;
  const int m0 = blockIdx.x * 64, n0 = blockIdx.y * 128;

  f32x4 acc[2][4];
#pragma unroll
  for (int mi = 0; mi < 2; ++mi)
#pragma unroll
    for (int ni = 0; ni < 4; ++ni)
#pragma unroll
      for (int r = 0; r < 4; ++r) acc[mi][ni][r] = 0.0f;

  const int ar = tid >> 2, ac = tid & 3;
  const char* gA = (const char*)A + (long)(m0 + ar) * 1024 + ((ac ^ (ar & 3)) << 4);
  const char* gW[2];
#pragma unroll
  for (int s = 0; s < 2; ++s) {
    const int rw = s * 64 + ar;
    gW[s] = (const char*)W + (long)(n0 + rw) * 1024 + ((ac ^ (rw & 3)) << 4);
  }
  const int wr = (wv >> 1) * 32, wc = (wv & 1) * 64;
  const int g = lane >> 4, cl = lane & 15;
  const int gx = (g ^ (cl & 3)) << 4;

  for (int kt = 0; kt < 16; ++kt) {
    GLOAD16(gA, (char*)As + tid * 16); gA += 64;
#pragma unroll
    for (int s = 0; s < 2; ++s) {
      GLOAD16(gW[s], (char*)Ws + (s * 256 + tid) * 16); gW[s] += 64;
    }
    __syncthreads();
    short8 af[2], bf[4];
#pragma unroll
    for (int i = 0; i < 2; ++i)
      af[i] = *(const short8*)((const char*)As + (wr + i * 16 + cl) * 64 + gx);
#pragma unroll
    for (int j = 0; j < 4; ++j)
      bf[j] = *(const short8*)((const char*)Ws + (wc + j * 16 + cl) * 64 + gx);
#pragma unroll
    for (int mi = 0; mi < 2; ++mi)
#pragma unroll
      for (int ni = 0; ni < 4; ++ni)
        acc[mi][ni] = __builtin_amdgcn_mfma_f32_16x16x32_bf16(af[mi], bf[ni], acc[mi][ni], 0, 0, 0);
    __syncthreads();
  }

#pragma unroll
  for (int mi = 0; mi < 2; ++mi)
#pragma unroll
    for (int ni = 0; ni < 4; ++ni)
#pragma unroll
      for (int r = 0; r < 4; ++r) {
        const int gm = m0 + wr + mi * 16 + g * 4 + r;
        const int gn = n0 + wc + ni * 16 + cl;
        out[((long)(gm & 1023) * BDIM + (gm >> 10)) * 512 + gn] = acc[mi][ni][r] + bias[gn];
      }
}

// ---------------------------------------------------------------- attention
// sigma-permuted swapped-QK^T flash, 128-k tiles, gload_lds staging with
// scalar tile base + loop-invariant lane offsets, fixed-m exp2 softmax
// (raw v_exp_f32 via builtin).
template<int NK>
__device__ __forceinline__ void attn_body(
    u16* __restrict__ Ks, u16* __restrict__ Vs,
    const u16* __restrict__ Q, const u16* __restrict__ KV,
    const u16* __restrict__ Vt, u16* __restrict__ X,
    const int h, const int sc, const int qt, const int b)
{
  const int tid = threadIdx.x;
  const int lane = tid & 63, wv = tid >> 6;
  const int g = lane >> 4, cl = lane & 15;

  const u16* qptr = Q + ((size_t)(b * 1024 + qt * 64 + wv * 16 + cl)) * 512
                      + (sc * 4 + h) * 64 + g * 8;
  const short8 qf0 = *(const short8*)qptr;
  const short8 qf1 = *(const short8*)(qptr + 32);

  f32x4 acc[4];   // acc[dj][r]: q = wv*16 + g*4 + r, d = dj*16 + cl
#pragma unroll
  for (int dj = 0; dj < 4; ++dj)
#pragma unroll
    for (int r = 0; r < 4; ++r) acc[dj][r] = 0.0f;
  float l = 0.0f;

  // wave-uniform bases; per-lane 32-bit inverse-swizzled offsets
  const char* kB = (const char*)(KV + (size_t)b * NK * 512 + h * 64);
  const char* vB = (const char*)(Vt + (size_t)((b * 4 + h) * 64) * NK);
  uint32_t koffL[4], voffL[4];
#pragma unroll
  for (int s = 0; s < 4; ++s) {
    const int c = s * 256 + tid;
    { const int rr = c >> 3, ch = c & 7;
      const int sig = (rr & 3) | ((rr >> 1) & 4);
      koffL[s] = rr * 1024 + ((ch ^ sig) << 4); }
    { const int rr = c >> 4, ch = c & 15;
      voffL[s] = rr * (NK * 2) + ((ch ^ (rr & 7)) << 4); }
  }

  int koffb[2][2];
#pragma unroll
  for (int half = 0; half < 2; ++half) {
    const int rest = ((cl & 12) << 1) + half * 4 + (cl & 3);
    const int swz = ((rest & 3) << 4) | ((rest & 8) << 3);
#pragma unroll
    for (int dh = 0; dh < 2; ++dh)
      koffb[half][dh] = rest * 128 + ((dh * 64 + g * 16) ^ swz);
  }
  int voffx[4][2];
#pragma unroll
  for (int dj = 0; dj < 4; ++dj) {
    const int vrow = dj * 16 + cl;
    const int base = vrow * 256 + ((g * 16) ^ ((vrow & 7) << 4));
    voffx[dj][0] = base; voffx[dj][1] = base ^ 64;
  }
  const int srcb = (lane & 48) | (g << 2);

  for (int kt = 0; kt < NK / 128; ++kt) {
    const char* kT = kB + (size_t)kt * 131072;   // 128 rows * 1024 B
    const char* vT = vB + (size_t)kt * 256;      // 128 k * 2 B
#pragma unroll
    for (int s = 0; s < 4; ++s) {
      GLOAD16(kT + koffL[s], (char*)Ks + s * 4096 + tid * 16);
      GLOAD16(vT + voffL[s], (char*)Vs + s * 4096 + tid * 16);
    }
    __syncthreads();

    // ---- S^T fragments
    f32x4 sv[8];
#pragma unroll
    for (int f = 0; f < 8; ++f)
#pragma unroll
      for (int r = 0; r < 4; ++r) sv[f][r] = 0.0f;
#pragma unroll
    for (int ks = 0; ks < 4; ++ks)
#pragma unroll
      for (int half = 0; half < 2; ++half) {
        const int f = ks * 2 + half;
        const short8 ak0 = *(const short8*)((const char*)Ks + ks * 4096 + koffb[half][0]);
        const short8 ak1 = *(const short8*)((const char*)Ks + ks * 4096 + koffb[half][1]);
        sv[f] = __builtin_amdgcn_mfma_f32_16x16x32_bf16(ak0, qf0, sv[f], 0, 0, 0);
        sv[f] = __builtin_amdgcn_mfma_f32_16x16x32_bf16(ak1, qf1, sv[f], 0, 0, 0);
      }

    // ---- fixed-m softmax: p = exp2(t) (raw v_exp_f32), l += sum
    float rs = 0.0f;
#pragma unroll
    for (int f = 0; f < 8; ++f)
#pragma unroll
      for (int r = 0; r < 4; ++r) {
        sv[f][r] = __builtin_amdgcn_exp2f(sv[f][r]);
        rs += sv[f][r];
      }
    rs += __shfl_xor(rs, 16);
    rs += __shfl_xor(rs, 32);
    l += rs;

    // ---- pack P into PV A-fragments (in-lane, 16 cvt_pk)
    u32x4 pw[4];
#pragma unroll
    for (int ks = 0; ks < 4; ++ks) {
      asm("v_cvt_pk_bf16_f32 %0, %1, %2" : "=v"(pw[ks][0]) : "v"(sv[2*ks][0]),   "v"(sv[2*ks][1]));
      asm("v_cvt_pk_bf16_f32 %0, %1, %2" : "=v"(pw[ks][1]) : "v"(sv[2*ks][2]),   "v"(sv[2*ks][3]));
      asm("v_cvt_pk_bf16_f32 %0, %1, %2" : "=v"(pw[ks][2]) : "v"(sv[2*ks+1][0]), "v"(sv[2*ks+1][1]));
      asm("v_cvt_pk_bf16_f32 %0, %1, %2" : "=v"(pw[ks][3]) : "v"(sv[2*ks+1][2]), "v"(sv[2*ks+1][3]));
    }

    // ---- O += P V
#pragma unroll
    for (int ks = 0; ks < 4; ++ks) {
      const short8 pa = __builtin_bit_cast(short8, pw[ks]);
#pragma unroll
      for (int dj = 0; dj < 4; ++dj) {
        const short8 bv = *(const short8*)((const char*)Vs +
                          ((ks >> 1) * 128 + voffx[dj][ks & 1]));
        acc[dj] = __builtin_amdgcn_mfma_f32_16x16x32_bf16(pa, bv, acc[dj], 0, 0, 0);
      }
    }
    __syncthreads();
  }

  // ---- epilogue: plain bf16 X
  const float inv = 1.0f / l;
  float invr[4];
#pragma unroll
  for (int r = 0; r < 4; ++r) invr[r] = __shfl(inv, srcb | r);
#pragma unroll
  for (int dj = 0; dj < 4; ++dj)
#pragma unroll
    for (int r = 0; r < 4; ++r) {
      const long gq = b * 1024 + qt * 64 + wv * 16 + g * 4 + r;
      X[gq * 512 + sc * 256 + h * 64 + dj * 16 + cl] = rne_bf16(acc[dj][r] * invr[r]);
    }
}

__global__ __launch_bounds__(256, 4) void attn_fused_kernel(
    const u16* __restrict__ Q,
    const u16* __restrict__ KV1, const u16* __restrict__ KV2,
    const u16* __restrict__ Vt1, const u16* __restrict__ Vt2,
    u16* __restrict__ X)
{
  __shared__ __align__(16) u16 Ks[128 * 64];
  __shared__ __align__(16) u16 Vs[64 * 128];
  // XCD-group swizzle: all 16 q-tiles of one (b, head, scale) land on one XCD
  const int d = blockIdx.x + (blockIdx.y << 4) + (blockIdx.z << 8);
  const int qt = (d >> 3) & 15;
  const int grp = (d & 7) + ((d >> 7) << 3);
  const int b = grp & 15, z = grp >> 4;
  if (z < 4) attn_body<1024>(Ks, Vs, Q, KV1, Vt1, X, z, 0, qt, b);
  else       attn_body<2048>(Ks, Vs, Q, KV2, Vt2, X, z - 4, 1, qt, b);
}

// ---------------------------------------------------------------- launch
extern "C" void kernel_launch(void* const* d_in, const int* in_sizes, int n_in,
                              void* d_out, int out_size, void* d_ws, size_t ws_size,
                              hipStream_t stream) {
  const float* query   = (const float*)d_in[0];
  const float* key     = (const float*)d_in[1];
  const float* key_pos = (const float*)d_in[2];
  const float* xyz_up  = (const float*)d_in[4];
  const float* Wq      = (const float*)d_in[5];
  const float* Wkv1    = (const float*)d_in[6];
  const float* Wkv2    = (const float*)d_in[7];
  const float* fp_w    = (const float*)d_in[8];
  const float* fp_b    = (const float*)d_in[9];
  const float* proj_w  = (const float*)d_in[10];
  const float* proj_b  = (const float*)d_in[11];

  char* ws = (char*)d_ws;
  const size_t MB = 1024 * 1024;
  u16*  Qa    = (u16*)(ws + 0);          // 16MB bf16 query; later X
  u16*  Ka    = (u16*)(ws + 16 * MB);    // 16MB bf16 key
  u16*  Qb    = (u16*)(ws + 32 * MB);    // 16MB
  u16*  KV1   = (u16*)(ws + 48 * MB);    // 16MB
  u16*  IN2   = (u16*)(ws + 64 * MB);    // 32MB interp; later KV2
  u16*  KEY2  = (u16*)(ws + 96 * MB);    // 32MB
  u16*  Vt1   = (u16*)(ws + 128 * MB);   //  8MB
  u16*  Vt2   = (u16*)(ws + 136 * MB);   // 16MB
  u16*  Wq2   = (u16*)(ws + 152 * MB);
  u16*  Wkv12 = (u16*)(ws + 152 * MB + 512 * 1024);
  u16*  proj2 = (u16*)(ws + 153 * MB);
  u16*  fpwb  = (u16*)(ws + 153 * MB + 512 * 1024);
  u16*  wkv2b = (u16*)(ws + 154 * MB);
  int*  idxb  = (int*)(ws + 155 * MB);
  float* wb   = (float*)(ws + 156 * MB);
  u16*  KV2   = IN2;
  u16*  X     = Qa;

  // 1. conversions + 3-NN (one launch, independent jobs)
  prep_kernel<<<dim3(9344), 256, 0, stream>>>(
      query, Qa, key, Ka, Wq, Wkv1, proj_w, fp_w, Wkv2,
      Wq2, Wkv12, proj2, fpwb, wkv2b, key_pos, xyz_up, idxb, wb);
  // 2. inverse-distance interpolation (bf16 gather from Ka)
  interp_bf16_kernel<<<dim3(8192), 256, 0, stream>>>(Ka, idxb, wb, IN2);
  // 3. fp-GEMM + q-GEMM + kv1-GEMM (one launch, BK=64)
  gemm_mega_kernel<<<dim3(2048), 256, 0, stream>>>(
      IN2, fpwb, fp_b, KEY2, Qa, Wq2, Qb, Ka, Wkv12, KV1);
  // 4. kv2-GEMM + Vt1 transpose (one launch)
  gemm_kv2_vt1_kernel<<<dim3(2048), 256, 0, stream>>>(KEY2, wkv2b, KV2, KV1, Vt1);
  // 5. Vt2 transpose
  vt2_kernel<<<dim3(32, 4, 16), 256, 0, stream>>>(KV2, Vt2);
  // 6. fused attention (both scales) -> X (plain bf16, overwrites Qa)
  attn_fused_kernel<<<dim3(16, 16, 8), 256, 0, stream>>>(Qb, KV1, KV2, Vt1, Vt2, X);
  // 7. output projection + final transpose (64-row tiles, 1024 blocks)
  gemm_proj64_kernel<<<dim3(256, 4), 256, 0, stream>>>(X, proj2, proj_b, (float*)d_out);
}

// Round 9
// 234.294 us; speedup vs baseline: 1.1961x; 1.1961x over previous
//
#include <hip/hip_runtime.h>
#include <cstdint>
#include <cstddef>

#define CD   512
#define BDIM 16
#define NQ   1024
#define NP   1024
#define NUP  2048

typedef unsigned short u16;
typedef short short8 __attribute__((ext_vector_type(8)));
typedef float f32x4  __attribute__((ext_vector_type(4)));
typedef uint32_t u32x4 __attribute__((ext_vector_type(4)));

#define GLOAD16(g, l) __builtin_amdgcn_global_load_lds( \
    (const __attribute__((address_space(1))) void*)(g), \
    (__attribute__((address_space(3))) void*)(l), 16, 0, 0)

__device__ __forceinline__ u16 rne_bf16(float x) {
  uint32_t u = __float_as_uint(x);
  return (u16)((u + 0x7fffu + ((u >> 16) & 1u)) >> 16);
}
__device__ __forceinline__ float bf2f(u16 v) {
  return __uint_as_float(((uint32_t)v) << 16);
}

// ---------------------------------------------------- prep: conversions + 3-NN
// bx < 8832: fp32->bf16 conversions (query, key, 5 weights).
// bx >= 8832: 2048 knn blocks: 16 points x 16 scanners x 64 keys,
//   float4-SoA LDS (conflict-free interleaved scan), shfl-xor lex merge.
__global__ __launch_bounds__(256) void prep_kernel(
    const float* __restrict__ query, u16* __restrict__ Qa,
    const float* __restrict__ key, u16* __restrict__ Ka,
    const float* __restrict__ Wq, const float* __restrict__ Wkv1,
    const float* __restrict__ projw, const float* __restrict__ fpw,
    const float* __restrict__ wkv2, u16* __restrict__ Wq2,
    u16* __restrict__ Wkv12, u16* __restrict__ proj2,
    u16* __restrict__ fpwb, u16* __restrict__ wkv2b,
    const float* __restrict__ key_pos, const float* __restrict__ xyz_up,
    int* __restrict__ idx_out, float* __restrict__ w_out)
{
  const int bx = blockIdx.x;
  const int tid = threadIdx.x;
  if (bx < 8832) {
    const float* in; u16* out; float scl = 1.0f; long u;
    if (bx < 8192) {
      in = (bx < 4096) ? query : key;
      out = (bx < 4096) ? Qa : Ka;
      u = (long)(bx & 4095) * 256 + tid;
    } else {
      const int job = (bx - 8192) >> 7;
      in  = (job == 0) ? Wq  : (job == 1) ? Wkv1  : (job == 2) ? projw : (job == 3) ? fpw  : wkv2;
      out = (job == 0) ? Wq2 : (job == 1) ? Wkv12 : (job == 2) ? proj2 : (job == 3) ? fpwb : wkv2b;
      if (job == 0) scl = 0.18033688011112042f;   // 0.125 * log2(e)
      u = (long)((bx - 8192) & 127) * 256 + tid;
    }
    const float* ip = in + u * 8;
    float v[8];
    *(float4*)&v[0] = *(const float4*)ip;
    *(float4*)&v[4] = *(const float4*)(ip + 4);
    short8 o;
#pragma unroll
    for (int i = 0; i < 8; ++i) o[i] = (short)rne_bf16(v[i] * scl);
    *(short8*)(out + u * 8) = o;
    return;
  }
  // ---- 3-NN path: block kb handles 16 points of batch b
  __shared__ __align__(16) float4 kp4[NP];
  const int kb = bx - 8832;
  const int b = kb >> 7;
  const int n0 = (kb & 127) * 16;
  const float* kpb = key_pos + (long)b * NP * 3;
#pragma unroll
  for (int s = 0; s < 4; ++s) {
    const int t = s * 256 + tid;
    kp4[t] = make_float4(kpb[t * 3], kpb[t * 3 + 1], kpb[t * 3 + 2], 0.0f);
  }
  __syncthreads();
  const int sc = tid & 15, pt = tid >> 4;
  const int n = n0 + pt;
  const float ux = xyz_up[(b * NUP + n) * 3 + 0];
  const float uy = xyz_up[(b * NUP + n) * 3 + 1];
  const float uz = xyz_up[(b * NUP + n) * 3 + 2];
  float e0 = 3.4e38f, e1 = 3.4e38f, e2 = 3.4e38f;
  int j0 = 0, j1 = 0, j2 = 0;
  // interleaved scan: j = it*16 + sc (ascending per scanner, bank-clean)
  for (int it = 0; it < 64; ++it) {
    const int j = it * 16 + sc;
    const float4 kv = kp4[j];
    const float dx = ux - kv.x, dy = uy - kv.y, dz = uz - kv.z;
    const float dd = dx * dx + dy * dy + dz * dz;
    if (dd < e2) {
      if (dd < e1) {
        e2 = e1; j2 = j1;
        if (dd < e0) { e1 = e0; j1 = j0; e0 = dd; j0 = j; }
        else         { e1 = dd; j1 = j; }
      } else { e2 = dd; j2 = j; }
    }
  }
  // lexicographic (d, idx) merge across the 16-lane scanner group
#pragma unroll
  for (int ms = 1; ms <= 8; ms <<= 1) {
    const float pd0 = __shfl_xor(e0, ms), pd1 = __shfl_xor(e1, ms), pd2 = __shfl_xor(e2, ms);
    const int   pi0 = __shfl_xor(j0, ms), pi1 = __shfl_xor(j1, ms), pi2 = __shfl_xor(j2, ms);
    float cd[3] = {pd0, pd1, pd2};
    int   ci[3] = {pi0, pi1, pi2};
#pragma unroll
    for (int t = 0; t < 3; ++t) {
      const float dd = cd[t]; const int jj = ci[t];
      if (dd < e2 || (dd == e2 && jj < j2)) {
        if (dd < e1 || (dd == e1 && jj < j1)) {
          e2 = e1; j2 = j1;
          if (dd < e0 || (dd == e0 && jj < j0)) { e1 = e0; j1 = j0; e0 = dd; j0 = jj; }
          else                                  { e1 = dd; j1 = jj; }
        } else { e2 = dd; j2 = jj; }
      }
    }
  }
  if (sc == 0) {
    const float w0 = 1.0f / (e0 + 1e-8f);
    const float w1 = 1.0f / (e1 + 1e-8f);
    const float w2 = 1.0f / (e2 + 1e-8f);
    const float inv = 1.0f / ((w0 + w1) + w2);
    const long r = (long)b * NUP + n;
    idx_out[r * 3 + 0] = j0; idx_out[r * 3 + 1] = j1; idx_out[r * 3 + 2] = j2;
    w_out[r * 3 + 0] = w0 * inv; w_out[r * 3 + 1] = w1 * inv; w_out[r * 3 + 2] = w2 * inv;
  }
}

// ------------------------------------------------- interp (bf16 in/out)
__global__ __launch_bounds__(256) void interp_bf16_kernel(
    const u16* __restrict__ Ka, const int* __restrict__ idx,
    const float* __restrict__ w, u16* __restrict__ out)
{
  const int t = threadIdx.x;
  const long r = (long)blockIdx.x * 4 + (t >> 6);
  const int j = t & 63;
  const int b = (int)(r >> 11);
  const int j0 = idx[r * 3 + 0], j1 = idx[r * 3 + 1], j2 = idx[r * 3 + 2];
  const float w0 = w[r * 3 + 0], w1 = w[r * 3 + 1], w2 = w[r * 3 + 2];
  const short8 a0 = *(const short8*)(Ka + ((long)j0 * BDIM + b) * CD + j * 8);
  const short8 a1 = *(const short8*)(Ka + ((long)j1 * BDIM + b) * CD + j * 8);
  const short8 a2 = *(const short8*)(Ka + ((long)j2 * BDIM + b) * CD + j * 8);
  short8 o;
#pragma unroll
  for (int i = 0; i < 8; ++i)
    o[i] = (short)rne_bf16(bf2f((u16)a0[i]) * w0 + bf2f((u16)a1[i]) * w1
                         + bf2f((u16)a2[i]) * w2);
  *(short8*)(out + r * CD + j * 8) = o;
}

// ---------------------------------------------------------------- GEMM BK=64
template<int AMODE, int OMODE, int KE>
__device__ __forceinline__ void gemm_body64(
    u16* __restrict__ As, u16* __restrict__ Ws,
    const u16* __restrict__ A, const u16* __restrict__ W,
    const float* __restrict__ bias, void* __restrict__ outv,
    const int m0, const int n0)
{
  const int tid = threadIdx.x;
  const int lane = tid & 63, wv = tid >> 6;
  const int rch = tid & 7;

  f32x4 acc[4][4];
#pragma unroll
  for (int mi = 0; mi < 4; ++mi)
#pragma unroll
    for (int ni = 0; ni < 4; ++ni)
#pragma unroll
      for (int r = 0; r < 4; ++r) acc[mi][ni][r] = 0.0f;

  const long rowb = (long)KE * 2;
  const char* gA[4]; const char* gW[4];
#pragma unroll
  for (int s = 0; s < 4; ++s) {
    const int row = s * 32 + (tid >> 3);
    const int gm = m0 + row;
    const long arow = (AMODE == 0) ? (long)gm : (long)(gm & 15) * 2048 + (gm >> 4);
    const int kb0 = (rch ^ (row & 7)) << 4;
    gA[s] = (const char*)A + arow * rowb + kb0;
    gW[s] = (const char*)W + (long)(n0 + row) * rowb + kb0;
  }
  const int wr = (wv >> 1) * 64, wc = (wv & 1) * 64;
  const int g = lane >> 4, cl = lane & 15;

  for (int kt = 0; kt < KE / 64; ++kt) {
#pragma unroll
    for (int s = 0; s < 4; ++s) {
      GLOAD16(gA[s], (char*)As + (s * 256 + tid) * 16);
      GLOAD16(gW[s], (char*)Ws + (s * 256 + tid) * 16);
      gA[s] += 128; gW[s] += 128;
    }
    __syncthreads();
#pragma unroll
    for (int kb = 0; kb < 2; ++kb) {
      short8 af[4], bf[4];
#pragma unroll
      for (int i = 0; i < 4; ++i) {
        const int ra = wr + i * 16 + cl;
        af[i] = *(const short8*)((const char*)As + ra * 128
                 + ((kb * 64 + g * 16) ^ ((ra & 7) << 4)));
        const int rb = wc + i * 16 + cl;
        bf[i] = *(const short8*)((const char*)Ws + rb * 128
                 + ((kb * 64 + g * 16) ^ ((rb & 7) << 4)));
      }
#pragma unroll
      for (int mi = 0; mi < 4; ++mi)
#pragma unroll
        for (int ni = 0; ni < 4; ++ni)
          acc[mi][ni] = __builtin_amdgcn_mfma_f32_16x16x32_bf16(af[mi], bf[ni], acc[mi][ni], 0, 0, 0);
    }
    __syncthreads();
  }

#pragma unroll
  for (int mi = 0; mi < 4; ++mi)
#pragma unroll
    for (int ni = 0; ni < 4; ++ni)
#pragma unroll
      for (int r = 0; r < 4; ++r) {
        const int gm = m0 + wr + mi * 16 + g * 4 + r;
        const int gn = n0 + wc + ni * 16 + cl;
        float v = acc[mi][ni][r];
        if (OMODE == 0) {
          ((u16*)outv)[(long)gm * 512 + gn] = rne_bf16(v);
        } else if (OMODE == 1) {
          v = fmaxf(v + bias[gn], 0.0f);
          ((u16*)outv)[(long)gm * 512 + gn] = rne_bf16(v);
        } else {
          v += bias[gn];
          ((float*)outv)[((long)(gm & 1023) * BDIM + (gm >> 10)) * 512 + gn] = v;
        }
      }
}

// fp-GEMM (1024 blocks) + q-GEMM (512) + kv1-GEMM (512) in one launch
__global__ __launch_bounds__(256) void gemm_mega_kernel(
    const u16* __restrict__ IN2, const u16* __restrict__ fpwb,
    const float* __restrict__ fp_b, u16* __restrict__ KEY2,
    const u16* __restrict__ Qa, const u16* __restrict__ Wq2, u16* __restrict__ Qb,
    const u16* __restrict__ Ka, const u16* __restrict__ Wkv12, u16* __restrict__ KV1)
{
  __shared__ __align__(16) u16 As[128 * 64];
  __shared__ __align__(16) u16 Ws[128 * 64];
  const int bid = blockIdx.x;
  if (bid < 1024) {
    gemm_body64<0, 1, 512>(As, Ws, IN2, fpwb, fp_b, KEY2, (bid >> 2) * 128, (bid & 3) * 128);
  } else if (bid < 1536) {
    const int t = bid - 1024;
    gemm_body64<0, 0, 512>(As, Ws, Qa, Wq2, nullptr, Qb, (t >> 2) * 128, (t & 3) * 128);
  } else {
    const int t = bid - 1536;
    gemm_body64<0, 0, 512>(As, Ws, Ka, Wkv12, nullptr, KV1, (t >> 2) * 128, (t & 3) * 128);
  }
}

// ------------------------------------------------- V transpose body
__device__ __forceinline__ void transpose_body(
    u16* __restrict__ L, const u16* __restrict__ KV, u16* __restrict__ Vt,
    const int NK, const int kt, const int h, const int b)
{
  const int t = threadIdx.x;
  {
    const int n = t >> 2, d0 = (t & 3) * 16;
    const u16* src = KV + ((size_t)b * NK + kt * 64 + n) * 512 + 256 + h * 64 + d0;
    *(short8*)&L[n * 68 + d0] = *(const short8*)src;
    *(short8*)&L[n * 68 + d0 + 8] = *(const short8*)(src + 8);
  }
  __syncthreads();
  const int d = t >> 2, n0 = (t & 3) * 16;
  short8 o0, o1;
#pragma unroll
  for (int i = 0; i < 8; ++i) {
    o0[i] = (short)L[(n0 + i) * 68 + d];
    o1[i] = (short)L[(n0 + 8 + i) * 68 + d];
  }
  u16* dst = Vt + ((size_t)((b * 4 + h) * 64 + d)) * NK + kt * 64 + n0;
  *(short8*)dst = o0; *(short8*)(dst + 8) = o1;
}

// kv2-GEMM (1024 blocks) + Vt1 transpose (1024 blocks): independent jobs
__global__ __launch_bounds__(256) void gemm_kv2_vt1_kernel(
    const u16* __restrict__ KEY2, const u16* __restrict__ wkv2b,
    u16* __restrict__ KV2,
    const u16* __restrict__ KV1, u16* __restrict__ Vt1)
{
  __shared__ __align__(16) u16 As[128 * 64];
  __shared__ __align__(16) u16 Ws[128 * 64];
  const int bid = blockIdx.x;
  if (bid < 1024) {
    gemm_body64<1, 0, 512>(As, Ws, KEY2, wkv2b, nullptr, KV2,
                           (bid >> 2) * 128, (bid & 3) * 128);
  } else {
    const int tb = bid - 1024;
    transpose_body(As, KV1, Vt1, 1024, tb & 15, (tb >> 4) & 3, tb >> 6);
  }
}

__global__ __launch_bounds__(256) void vt2_kernel(
    const u16* __restrict__ KV2, u16* __restrict__ Vt2)
{
  __shared__ u16 L[64 * 68];
  transpose_body(L, KV2, Vt2, 2048, blockIdx.x, blockIdx.y, blockIdx.z);
}

// ------------------------------------------------- proj GEMM, 64x128 tiles
__global__ __launch_bounds__(256) void gemm_proj64_kernel(
    const u16* __restrict__ A, const u16* __restrict__ W,
    const float* __restrict__ bias, float* __restrict__ out)
{
  __shared__ __align__(16) u16 As[64 * 32];
  __shared__ __align__(16) u16 Ws[128 * 32];
  const int tid = threadIdx.x;
  const int lane = tid & 63, wv = tid >> 6;
  const int m0 = blockIdx.x * 64, n0 = blockIdx.y * 128;

  f32x4 acc[2][4];
#pragma unroll
  for (int mi = 0; mi < 2; ++mi)
#pragma unroll
    for (int ni = 0; ni < 4; ++ni)
#pragma unroll
      for (int r = 0; r < 4; ++r) acc[mi][ni][r] = 0.0f;

  const int ar = tid >> 2, ac = tid & 3;
  const char* gA = (const char*)A + (long)(m0 + ar) * 1024 + ((ac ^ (ar & 3)) << 4);
  const char* gW[2];
#pragma unroll
  for (int s = 0; s < 2; ++s) {
    const int rw = s * 64 + ar;
    gW[s] = (const char*)W + (long)(n0 + rw) * 1024 + ((ac ^ (rw & 3)) << 4);
  }
  const int wr = (wv >> 1) * 32, wc = (wv & 1) * 64;
  const int g = lane >> 4, cl = lane & 15;
  const int gx = (g ^ (cl & 3)) << 4;

  for (int kt = 0; kt < 16; ++kt) {
    GLOAD16(gA, (char*)As + tid * 16); gA += 64;
#pragma unroll
    for (int s = 0; s < 2; ++s) {
      GLOAD16(gW[s], (char*)Ws + (s * 256 + tid) * 16); gW[s] += 64;
    }
    __syncthreads();
    short8 af[2], bf[4];
#pragma unroll
    for (int i = 0; i < 2; ++i)
      af[i] = *(const short8*)((const char*)As + (wr + i * 16 + cl) * 64 + gx);
#pragma unroll
    for (int j = 0; j < 4; ++j)
      bf[j] = *(const short8*)((const char*)Ws + (wc + j * 16 + cl) * 64 + gx);
#pragma unroll
    for (int mi = 0; mi < 2; ++mi)
#pragma unroll
      for (int ni = 0; ni < 4; ++ni)
        acc[mi][ni] = __builtin_amdgcn_mfma_f32_16x16x32_bf16(af[mi], bf[ni], acc[mi][ni], 0, 0, 0);
    __syncthreads();
  }

#pragma unroll
  for (int mi = 0; mi < 2; ++mi)
#pragma unroll
    for (int ni = 0; ni < 4; ++ni)
#pragma unroll
      for (int r = 0; r < 4; ++r) {
        const int gm = m0 + wr + mi * 16 + g * 4 + r;
        const int gn = n0 + wc + ni * 16 + cl;
        out[((long)(gm & 1023) * BDIM + (gm >> 10)) * 512 + gn] = acc[mi][ni][r] + bias[gn];
      }
}

// ---------------------------------------------------------------- attention
template<int NK>
__device__ __forceinline__ void attn_body(
    u16* __restrict__ Ks, u16* __restrict__ Vs,
    const u16* __restrict__ Q, const u16* __restrict__ KV,
    const u16* __restrict__ Vt, u16* __restrict__ X,
    const int h, const int sc, const int qt, const int b)
{
  const int tid = threadIdx.x;
  const int lane = tid & 63, wv = tid >> 6;
  const int g = lane >> 4, cl = lane & 15;

  const u16* qptr = Q + ((size_t)(b * 1024 + qt * 64 + wv * 16 + cl)) * 512
                      + (sc * 4 + h) * 64 + g * 8;
  const short8 qf0 = *(const short8*)qptr;
  const short8 qf1 = *(const short8*)(qptr + 32);

  f32x4 acc[4];   // acc[dj][r]: q = wv*16 + g*4 + r, d = dj*16 + cl
#pragma unroll
  for (int dj = 0; dj < 4; ++dj)
#pragma unroll
    for (int r = 0; r < 4; ++r) acc[dj][r] = 0.0f;
  float l = 0.0f;

  const char* kB = (const char*)(KV + (size_t)b * NK * 512 + h * 64);
  const char* vB = (const char*)(Vt + (size_t)((b * 4 + h) * 64) * NK);
  uint32_t koffL[4], voffL[4];
#pragma unroll
  for (int s = 0; s < 4; ++s) {
    const int c = s * 256 + tid;
    { const int rr = c >> 3, ch = c & 7;
      const int sig = (rr & 3) | ((rr >> 1) & 4);
      koffL[s] = rr * 1024 + ((ch ^ sig) << 4); }
    { const int rr = c >> 4, ch = c & 15;
      voffL[s] = rr * (NK * 2) + ((ch ^ (rr & 7)) << 4); }
  }

  int koffb[2][2];
#pragma unroll
  for (int half = 0; half < 2; ++half) {
    const int rest = ((cl & 12) << 1) + half * 4 + (cl & 3);
    const int swz = ((rest & 3) << 4) | ((rest & 8) << 3);
#pragma unroll
    for (int dh = 0; dh < 2; ++dh)
      koffb[half][dh] = rest * 128 + ((dh * 64 + g * 16) ^ swz);
  }
  int voffx[4][2];
#pragma unroll
  for (int dj = 0; dj < 4; ++dj) {
    const int vrow = dj * 16 + cl;
    const int base = vrow * 256 + ((g * 16) ^ ((vrow & 7) << 4));
    voffx[dj][0] = base; voffx[dj][1] = base ^ 64;
  }
  const int srcb = (lane & 48) | (g << 2);

  for (int kt = 0; kt < NK / 128; ++kt) {
    const char* kT = kB + (size_t)kt * 131072;
    const char* vT = vB + (size_t)kt * 256;
#pragma unroll
    for (int s = 0; s < 4; ++s) {
      GLOAD16(kT + koffL[s], (char*)Ks + s * 4096 + tid * 16);
      GLOAD16(vT + voffL[s], (char*)Vs + s * 4096 + tid * 16);
    }
    __syncthreads();

    // ---- S^T fragments
    f32x4 sv[8];
#pragma unroll
    for (int f = 0; f < 8; ++f)
#pragma unroll
      for (int r = 0; r < 4; ++r) sv[f][r] = 0.0f;
    __builtin_amdgcn_s_setprio(1);
#pragma unroll
    for (int ks = 0; ks < 4; ++ks)
#pragma unroll
      for (int half = 0; half < 2; ++half) {
        const int f = ks * 2 + half;
        const short8 ak0 = *(const short8*)((const char*)Ks + ks * 4096 + koffb[half][0]);
        const short8 ak1 = *(const short8*)((const char*)Ks + ks * 4096 + koffb[half][1]);
        sv[f] = __builtin_amdgcn_mfma_f32_16x16x32_bf16(ak0, qf0, sv[f], 0, 0, 0);
        sv[f] = __builtin_amdgcn_mfma_f32_16x16x32_bf16(ak1, qf1, sv[f], 0, 0, 0);
      }
    __builtin_amdgcn_s_setprio(0);

    // ---- fixed-m softmax: p = exp2(t) (raw v_exp_f32), l += sum
    float rs = 0.0f;
#pragma unroll
    for (int f = 0; f < 8; ++f)
#pragma unroll
      for (int r = 0; r < 4; ++r) {
        sv[f][r] = __builtin_amdgcn_exp2f(sv[f][r]);
        rs += sv[f][r];
      }
    rs += __shfl_xor(rs, 16);
    rs += __shfl_xor(rs, 32);
    l += rs;

    // ---- pack P into PV A-fragments (in-lane, 16 cvt_pk)
    u32x4 pw[4];
#pragma unroll
    for (int ks = 0; ks < 4; ++ks) {
      asm("v_cvt_pk_bf16_f32 %0, %1, %2" : "=v"(pw[ks][0]) : "v"(sv[2*ks][0]),   "v"(sv[2*ks][1]));
      asm("v_cvt_pk_bf16_f32 %0, %1, %2" : "=v"(pw[ks][1]) : "v"(sv[2*ks][2]),   "v"(sv[2*ks][3]));
      asm("v_cvt_pk_bf16_f32 %0, %1, %2" : "=v"(pw[ks][2]) : "v"(sv[2*ks+1][0]), "v"(sv[2*ks+1][1]));
      asm("v_cvt_pk_bf16_f32 %0, %1, %2" : "=v"(pw[ks][3]) : "v"(sv[2*ks+1][2]), "v"(sv[2*ks+1][3]));
    }

    // ---- O += P V
    __builtin_amdgcn_s_setprio(1);
#pragma unroll
    for (int ks = 0; ks < 4; ++ks) {
      const short8 pa = __builtin_bit_cast(short8, pw[ks]);
#pragma unroll
      for (int dj = 0; dj < 4; ++dj) {
        const short8 bv = *(const short8*)((const char*)Vs +
                          ((ks >> 1) * 128 + voffx[dj][ks & 1]));
        acc[dj] = __builtin_amdgcn_mfma_f32_16x16x32_bf16(pa, bv, acc[dj], 0, 0, 0);
      }
    }
    __builtin_amdgcn_s_setprio(0);
    __syncthreads();
  }

  // ---- epilogue: plain bf16 X
  const float inv = 1.0f / l;
  float invr[4];
#pragma unroll
  for (int r = 0; r < 4; ++r) invr[r] = __shfl(inv, srcb | r);
#pragma unroll
  for (int dj = 0; dj < 4; ++dj)
#pragma unroll
    for (int r = 0; r < 4; ++r) {
      const long gq = b * 1024 + qt * 64 + wv * 16 + g * 4 + r;
      X[gq * 512 + sc * 256 + h * 64 + dj * 16 + cl] = rne_bf16(acc[dj][r] * invr[r]);
    }
}

__global__ __launch_bounds__(256, 4) void attn_fused_kernel(
    const u16* __restrict__ Q,
    const u16* __restrict__ KV1, const u16* __restrict__ KV2,
    const u16* __restrict__ Vt1, const u16* __restrict__ Vt2,
    u16* __restrict__ X)
{
  __shared__ __align__(16) u16 Ks[128 * 64];
  __shared__ __align__(16) u16 Vs[64 * 128];
  // XCD-group swizzle: all 16 q-tiles of one (b, head, scale) land on one XCD
  const int d = blockIdx.x + (blockIdx.y << 4) + (blockIdx.z << 8);
  const int qt = (d >> 3) & 15;
  const int grp = (d & 7) + ((d >> 7) << 3);
  const int b = grp & 15, z = grp >> 4;
  if (z < 4) attn_body<1024>(Ks, Vs, Q, KV1, Vt1, X, z, 0, qt, b);
  else       attn_body<2048>(Ks, Vs, Q, KV2, Vt2, X, z - 4, 1, qt, b);
}

// ---------------------------------------------------------------- launch
extern "C" void kernel_launch(void* const* d_in, const int* in_sizes, int n_in,
                              void* d_out, int out_size, void* d_ws, size_t ws_size,
                              hipStream_t stream) {
  const float* query   = (const float*)d_in[0];
  const float* key     = (const float*)d_in[1];
  const float* key_pos = (const float*)d_in[2];
  const float* xyz_up  = (const float*)d_in[4];
  const float* Wq      = (const float*)d_in[5];
  const float* Wkv1    = (const float*)d_in[6];
  const float* Wkv2    = (const float*)d_in[7];
  const float* fp_w    = (const float*)d_in[8];
  const float* fp_b    = (const float*)d_in[9];
  const float* proj_w  = (const float*)d_in[10];
  const float* proj_b  = (const float*)d_in[11];

  char* ws = (char*)d_ws;
  const size_t MB = 1024 * 1024;
  u16*  Qa    = (u16*)(ws + 0);          // 16MB bf16 query; later X
  u16*  Ka    = (u16*)(ws + 16 * MB);    // 16MB bf16 key
  u16*  Qb    = (u16*)(ws + 32 * MB);    // 16MB
  u16*  KV1   = (u16*)(ws + 48 * MB);    // 16MB
  u16*  IN2   = (u16*)(ws + 64 * MB);    // 32MB interp; later KV2
  u16*  KEY2  = (u16*)(ws + 96 * MB);    // 32MB
  u16*  Vt1   = (u16*)(ws + 128 * MB);   //  8MB
  u16*  Vt2   = (u16*)(ws + 136 * MB);   // 16MB
  u16*  Wq2   = (u16*)(ws + 152 * MB);
  u16*  Wkv12 = (u16*)(ws + 152 * MB + 512 * 1024);
  u16*  proj2 = (u16*)(ws + 153 * MB);
  u16*  fpwb  = (u16*)(ws + 153 * MB + 512 * 1024);
  u16*  wkv2b = (u16*)(ws + 154 * MB);
  int*  idxb  = (int*)(ws + 155 * MB);
  float* wb   = (float*)(ws + 156 * MB);
  u16*  KV2   = IN2;
  u16*  X     = Qa;

  // 1. conversions + 3-NN (one launch; knn now 2048 blocks, conflict-free)
  prep_kernel<<<dim3(10880), 256, 0, stream>>>(
      query, Qa, key, Ka, Wq, Wkv1, proj_w, fp_w, Wkv2,
      Wq2, Wkv12, proj2, fpwb, wkv2b, key_pos, xyz_up, idxb, wb);
  // 2. inverse-distance interpolation (bf16 gather from Ka)
  interp_bf16_kernel<<<dim3(8192), 256, 0, stream>>>(Ka, idxb, wb, IN2);
  // 3. fp-GEMM + q-GEMM + kv1-GEMM (one launch, BK=64)
  gemm_mega_kernel<<<dim3(2048), 256, 0, stream>>>(
      IN2, fpwb, fp_b, KEY2, Qa, Wq2, Qb, Ka, Wkv12, KV1);
  // 4. kv2-GEMM + Vt1 transpose (one launch)
  gemm_kv2_vt1_kernel<<<dim3(2048), 256, 0, stream>>>(KEY2, wkv2b, KV2, KV1, Vt1);
  // 5. Vt2 transpose
  vt2_kernel<<<dim3(32, 4, 16), 256, 0, stream>>>(KV2, Vt2);
  // 6. fused attention (both scales) -> X (plain bf16, overwrites Qa)
  attn_fused_kernel<<<dim3(16, 16, 8), 256, 0, stream>>>(Qb, KV1, KV2, Vt1, Vt2, X);
  // 7. output projection + final transpose (64-row tiles, 1024 blocks)
  gemm_proj64_kernel<<<dim3(256, 4), 256, 0, stream>>>(X, proj2, proj_b, (float*)d_out);
}